// Round 12
// baseline (77.322 us; speedup 1.0000x reference)
//
#include <hip/hip_runtime.h>
#include <math.h>

#define NFEAT 16
#define NRULE 64
#define TPW 2        // 16-sample tiles per wave

typedef _Float16 half8 __attribute__((ext_vector_type(8)));
typedef float    f4    __attribute__((ext_vector_type(4)));
union F4H8 { float4 f; half8 h; };

// Single fused kernel, NO runtime path selection (R10/R11 lesson: the in-wave
// uniformity-flag branch silently selected the fallback twice; mechanism never
// localized -> eliminate the branch). The MFMA formulation is fully general in
// sigma via a third GEMM pair for the quadratic term:
//   logw*log2e = X^2 . C  +  X . B  +  K
//   C = -inv*log2e, B = 2*inv*mu*log2e, K = -log2e * sum inv*mu^2,
//   inv = 1/(2 sigma^2)  (rcpf approx, ~1e-7 rel, threshold is 8.8e-3)
// f16-split GEMM (R9-verified layouts): A = [Vh | Vl] (K=32), B1 = [Wh;Wh],
// B2 = [Wl;Wl] => mfma(A,B1)+mfma(A,B2) = V.W to ~fp32 accuracy.
// A-frag: m = lane&15 (sample), k = quad*8+j; quads 0,1 = high, 2,3 = low.
// B-frag: n = lane&15 (rule), same k -> feats fb = (quad&1)*8, both K-halves
//         hold the same rule weights (the [W;W] duplication).
// C/D:    col = lane&15 (rule), row = quad*4+reg (sample).
__global__ __launch_bounds__(256, 3) void fuzzy_fused(const float* __restrict__ x,
                                                      const float* __restrict__ mu,
                                                      const float* __restrict__ sigma,
                                                      const float* __restrict__ rho,
                                                      float* __restrict__ out, int n) {
    const float L2E = 1.4426950408889634f;
    const int tid  = threadIdx.x;
    const int L    = tid & 63;
    const int quad = L >> 4;
    const int m    = L & 15;
    const int wv   = __builtin_amdgcn_readfirstlane(tid >> 6);
    const int fb   = (quad & 1) * 8;

    // ---- issue x loads first (in flight during the fragment build) ----
    const int tbase = (blockIdx.x * 4 + wv) * TPW;
    float4 xa[TPW], xb[TPW];
#pragma unroll
    for (int t = 0; t < TPW; ++t) {
        int tb = (tbase + t) * 16;
        int sc = tb + m < n ? tb + m : n - 1;
        const float4* xp = (const float4*)(x + (size_t)sc * NFEAT + fb);
        xa[t] = xp[0]; xb[t] = xp[1];
    }

    // ---- in-register fragment build (general in sigma; no flag) ----
    F4H8 c1[4], c2[4], b1[4], b2[4], r1[4], r2[4];
    float Kv[4], Bv[4];
#pragma unroll
    for (int T = 0; T < 4; ++T) {
        int rule = T * 16 + m;
        const float* mrow = mu    + rule * NFEAT + fb;
        const float* srow = sigma + rule * NFEAT + fb;
        const float* rrow = rho   + rule * (NFEAT + 1) + fb;
        float kp = 0.0f;
#pragma unroll
        for (int j = 0; j < 8; ++j) {
            float mm = mrow[j], ss = srow[j], rr = rrow[j];
            float iv = __builtin_amdgcn_rcpf(2.0f * ss * ss);   // 1/(2s^2)
            float Cw = -iv * L2E;
            _Float16 ch = (_Float16)Cw;
            c1[T].h[j] = ch;
            c2[T].h[j] = (_Float16)(Cw - (float)ch);
            float Bw = 2.0f * iv * mm * L2E;
            _Float16 bh = (_Float16)Bw;
            b1[T].h[j] = bh;
            b2[T].h[j] = (_Float16)(Bw - (float)bh);
            _Float16 rh_ = (_Float16)rr;
            r1[T].h[j] = rh_;
            r2[T].h[j] = (_Float16)(rr - (float)rh_);
            kp = fmaf(iv * mm, mm, kp);
        }
        // other 8 features' K-partial lives in quad^1 (xor mask 16)
        Kv[T] = -(kp + __shfl_xor(kp, 16)) * L2E;
        Bv[T] = rho[rule * (NFEAT + 1) + NFEAT];
    }

#pragma unroll
    for (int t = 0; t < TPW; ++t) {
        int tb = (tbase + t) * 16;
        if (tb >= n) break;
        float xv[8] = {xa[t].x, xa[t].y, xa[t].z, xa[t].w,
                       xb[t].x, xb[t].y, xb[t].z, xb[t].w};
        F4H8 a1, a2;                        // X and X^2 fragments (f16-split)
#pragma unroll
        for (int j = 0; j < 8; ++j) {
            float v = xv[j];
            _Float16 h = (_Float16)v;
            a1.h[j] = (quad < 2) ? h : (_Float16)(v - (float)h);
            float s = v * v;
            _Float16 hs = (_Float16)s;
            a2.h[j] = (quad < 2) ? hs : (_Float16)(s - (float)hs);
        }

        f4 nsum = {0.f, 0.f, 0.f, 0.f}, dsum = {0.f, 0.f, 0.f, 0.f};
#pragma unroll
        for (int T = 0; T < 4; ++T) {
            f4 z4 = {0.f, 0.f, 0.f, 0.f};
            f4 accG = __builtin_amdgcn_mfma_f32_16x16x32_f16(a2.h, c1[T].h, z4, 0, 0, 0);
            accG    = __builtin_amdgcn_mfma_f32_16x16x32_f16(a2.h, c2[T].h, accG, 0, 0, 0);
            accG    = __builtin_amdgcn_mfma_f32_16x16x32_f16(a1.h, b1[T].h, accG, 0, 0, 0);
            accG    = __builtin_amdgcn_mfma_f32_16x16x32_f16(a1.h, b2[T].h, accG, 0, 0, 0);
            f4 accZ = __builtin_amdgcn_mfma_f32_16x16x32_f16(a1.h, r1[T].h, z4, 0, 0, 0);
            accZ    = __builtin_amdgcn_mfma_f32_16x16x32_f16(a1.h, r2[T].h, accZ, 0, 0, 0);
#pragma unroll
            for (int p = 0; p < 4; ++p) {
                float l = accG[p] + Kv[T];
                float w = __builtin_amdgcn_exp2f(l);
                float zf = accZ[p] + Bv[T];
                nsum[p] = fmaf(zf, w, nsum[p]);
                dsum[p] += w;
            }
        }
        // reduce over the 16 rule-columns (lanes differing in low 4 bits)
#pragma unroll
        for (int d = 1; d < 16; d <<= 1) {
#pragma unroll
            for (int p = 0; p < 4; ++p) {
                nsum[p] += __shfl_xor(nsum[p], d);
                dsum[p] += __shfl_xor(dsum[p], d);
            }
        }
        if (m == 0) {                       // 4 writer lanes; rows quad*4+p
            float4 o;
            o.x = nsum[0] * __builtin_amdgcn_rcpf(dsum[0] + 1e-13f);
            o.y = nsum[1] * __builtin_amdgcn_rcpf(dsum[1] + 1e-13f);
            o.z = nsum[2] * __builtin_amdgcn_rcpf(dsum[2] + 1e-13f);
            o.w = nsum[3] * __builtin_amdgcn_rcpf(dsum[3] + 1e-13f);
            ((float4*)(out + tb))[quad] = o;
        }
    }
}

extern "C" void kernel_launch(void* const* d_in, const int* in_sizes, int n_in,
                              void* d_out, int out_size, void* d_ws, size_t ws_size,
                              hipStream_t stream) {
    const float* x     = (const float*)d_in[0];   // [N,16]
    const float* mu    = (const float*)d_in[1];   // [64,16]
    const float* sigma = (const float*)d_in[2];   // [64,16]
    const float* rho   = (const float*)d_in[3];   // [64,17]
    float* out = (float*)d_out;

    int n = in_sizes[0] / NFEAT;                  // 131072

    int blocks = (n + 16 * 4 * TPW - 1) / (16 * 4 * TPW);  // 1024
    fuzzy_fused<<<blocks, 256, 0, stream>>>(x, mu, sigma, rho, out, n);
}

// Round 13
// 73.349 us; speedup vs baseline: 1.0542x; 1.0542x over previous
//
#include <hip/hip_runtime.h>
#include <math.h>

#define NFEAT 16
#define TPW 2        // 16-sample tiles per wave

typedef _Float16 half8 __attribute__((ext_vector_type(8)));
typedef float    f4    __attribute__((ext_vector_type(4)));
union F4H8 { float4 f; half8 h; };

// Single fused, branch-free general kernel (R12 numerics — verified absmax
// 9.09e-13 on HW). MFMA formulation general in sigma:
//   logw*log2e = X^2 . C + X . B + K
//   C = -inv*L2E, B = 2*inv*mu*L2E, K = -L2E*sum inv*mu^2, inv = 1/(2 s^2)
// f16-split GEMM: A=[Vh|Vl] (K=32) vs B1=[Wh;Wh], B2=[Wl;Wl] -> V.W @ fp32.
// A-frag: m=lane&15 (sample), k=quad*8+j; quads 0,1 = high, 2,3 = low half.
// B-frag: n=lane&15 (rule), feats fb=(quad&1)*8. C/D: col=rule, row=quad*4+p.
//
// R12 lesson: 96 VGPRs of fragments forced launch_bounds(256,3) -> 768
// resident blocks vs 1024-grid -> tail wave. Fix: process rules in two
// 32-rule phases (unroll 1!) so only half the fragments are live ->
// ~100 VGPR -> 4 blocks/CU, 1024 = 4*256 exact, no tail.
__global__ __launch_bounds__(256, 4) void fuzzy_fused(const float* __restrict__ x,
                                                      const float* __restrict__ mu,
                                                      const float* __restrict__ sigma,
                                                      const float* __restrict__ rho,
                                                      float* __restrict__ out, int n) {
    const float L2E = 1.4426950408889634f;
    const int tid  = threadIdx.x;
    const int L    = tid & 63;
    const int quad = L >> 4;
    const int m    = L & 15;
    const int wv   = __builtin_amdgcn_readfirstlane(tid >> 6);
    const int fb   = (quad & 1) * 8;

    const int tbase = (blockIdx.x * 4 + wv) * TPW;

    // ---- load x and build A fragments (X and X^2, f16-split) up front ----
    F4H8 a1[TPW], a2[TPW];
#pragma unroll
    for (int t = 0; t < TPW; ++t) {
        int tb = (tbase + t) * 16;
        int sc = tb + m < n ? tb + m : n - 1;
        const float4* xp = (const float4*)(x + (size_t)sc * NFEAT + fb);
        float4 va = xp[0], vb = xp[1];
        float xv[8] = {va.x, va.y, va.z, va.w, vb.x, vb.y, vb.z, vb.w};
#pragma unroll
        for (int j = 0; j < 8; ++j) {
            float v = xv[j];
            _Float16 h = (_Float16)v;
            a1[t].h[j] = (quad < 2) ? h : (_Float16)(v - (float)h);
            float s = v * v;
            _Float16 hs = (_Float16)s;
            a2[t].h[j] = (quad < 2) ? hs : (_Float16)(s - (float)hs);
        }
    }

    f4 nsum[TPW], dsum[TPW];
#pragma unroll
    for (int t = 0; t < TPW; ++t) {
        nsum[t] = (f4){0.f, 0.f, 0.f, 0.f};
        dsum[t] = (f4){0.f, 0.f, 0.f, 0.f};
    }

#pragma unroll 1   // MUST stay rolled: keeps only one phase's frags live
    for (int ph = 0; ph < 2; ++ph) {
        // ---- build fragments for this phase's 32 rules (2 N-tiles) ----
        F4H8 c1[2], c2[2], b1[2], b2[2], r1[2], r2[2];
        float Kv[2], Bv[2];
#pragma unroll
        for (int T2 = 0; T2 < 2; ++T2) {
            int rule = (ph * 2 + T2) * 16 + m;
            const float* mrow = mu    + rule * NFEAT + fb;
            const float* srow = sigma + rule * NFEAT + fb;
            const float* rrow = rho   + rule * (NFEAT + 1) + fb;
            float kp = 0.0f;
#pragma unroll
            for (int j = 0; j < 8; ++j) {
                float mm = mrow[j], ss = srow[j], rr = rrow[j];
                float iv = __builtin_amdgcn_rcpf(2.0f * ss * ss);   // 1/(2s^2)
                float Cw = -iv * L2E;
                _Float16 ch = (_Float16)Cw;
                c1[T2].h[j] = ch;
                c2[T2].h[j] = (_Float16)(Cw - (float)ch);
                float Bw = 2.0f * iv * mm * L2E;
                _Float16 bh = (_Float16)Bw;
                b1[T2].h[j] = bh;
                b2[T2].h[j] = (_Float16)(Bw - (float)bh);
                _Float16 rh_ = (_Float16)rr;
                r1[T2].h[j] = rh_;
                r2[T2].h[j] = (_Float16)(rr - (float)rh_);
                kp = fmaf(iv * mm, mm, kp);
            }
            Kv[T2] = -(kp + __shfl_xor(kp, 16)) * L2E;  // other 8 feats: quad^1
            Bv[T2] = rho[rule * (NFEAT + 1) + NFEAT];
        }

        // ---- MFMA rule loop over this phase ----
#pragma unroll
        for (int t = 0; t < TPW; ++t) {
#pragma unroll
            for (int T2 = 0; T2 < 2; ++T2) {
                f4 z4 = (f4){0.f, 0.f, 0.f, 0.f};
                f4 accG = __builtin_amdgcn_mfma_f32_16x16x32_f16(a2[t].h, c1[T2].h, z4, 0, 0, 0);
                accG    = __builtin_amdgcn_mfma_f32_16x16x32_f16(a2[t].h, c2[T2].h, accG, 0, 0, 0);
                accG    = __builtin_amdgcn_mfma_f32_16x16x32_f16(a1[t].h, b1[T2].h, accG, 0, 0, 0);
                accG    = __builtin_amdgcn_mfma_f32_16x16x32_f16(a1[t].h, b2[T2].h, accG, 0, 0, 0);
                f4 accZ = __builtin_amdgcn_mfma_f32_16x16x32_f16(a1[t].h, r1[T2].h, z4, 0, 0, 0);
                accZ    = __builtin_amdgcn_mfma_f32_16x16x32_f16(a1[t].h, r2[T2].h, accZ, 0, 0, 0);
#pragma unroll
                for (int p = 0; p < 4; ++p) {
                    float l = accG[p] + Kv[T2];
                    float w = __builtin_amdgcn_exp2f(l);
                    float zf = accZ[p] + Bv[T2];
                    nsum[t][p] = fmaf(zf, w, nsum[t][p]);
                    dsum[t][p] += w;
                }
            }
        }
    }

    // ---- reduce over the 16 rule-columns and write ----
#pragma unroll
    for (int t = 0; t < TPW; ++t) {
        int tb = (tbase + t) * 16;
        if (tb >= n) break;
        f4 nn = nsum[t], dd = dsum[t];
#pragma unroll
        for (int d = 1; d < 16; d <<= 1) {
#pragma unroll
            for (int p = 0; p < 4; ++p) {
                nn[p] += __shfl_xor(nn[p], d);
                dd[p] += __shfl_xor(dd[p], d);
            }
        }
        if (m == 0) {                       // 4 writer lanes; rows quad*4+p
            float4 o;
            o.x = nn[0] * __builtin_amdgcn_rcpf(dd[0] + 1e-13f);
            o.y = nn[1] * __builtin_amdgcn_rcpf(dd[1] + 1e-13f);
            o.z = nn[2] * __builtin_amdgcn_rcpf(dd[2] + 1e-13f);
            o.w = nn[3] * __builtin_amdgcn_rcpf(dd[3] + 1e-13f);
            ((float4*)(out + tb))[quad] = o;
        }
    }
}

extern "C" void kernel_launch(void* const* d_in, const int* in_sizes, int n_in,
                              void* d_out, int out_size, void* d_ws, size_t ws_size,
                              hipStream_t stream) {
    const float* x     = (const float*)d_in[0];   // [N,16]
    const float* mu    = (const float*)d_in[1];   // [64,16]
    const float* sigma = (const float*)d_in[2];   // [64,16]
    const float* rho   = (const float*)d_in[3];   // [64,17]
    float* out = (float*)d_out;

    int n = in_sizes[0] / NFEAT;                  // 131072

    int blocks = (n + 16 * 4 * TPW - 1) / (16 * 4 * TPW);  // 1024 = 4 per CU
    fuzzy_fused<<<blocks, 256, 0, stream>>>(x, mu, sigma, rho, out, n);
}